// Round 1
// baseline (402.087 us; speedup 1.0000x reference)
//
#include <hip/hip_runtime.h>

// BitNet-style fused 3-layer MLP for MI355X (gfx950).
//
// Strategy: activations quantize to integers in [-128,127], weights to
// ternary {-1,0,1}; both are exact in fp16, and mfma_f32_16x16x32_f16
// accumulates integer products exactly in fp32 (|sum| << 2^24). So the
// matmuls are EXACT; only reduction ordering + rint boundaries differ from
// the numpy reference (noise ~1e-3 vs threshold 4.56e-2).
//
// ws layout:
//   [0,24)      double sums[3]  (Σ|w| per tensor; zeroed via hipMemsetAsync)
//   256         t1: 128 x 832 fp16 ternary w1 (K padded 784->832 w/ zeros)
//   213248      t2: 64 x 128 fp16 ternary w2
//   229632      t3: 16 x 64  fp16 ternary w3 (rows 10..15 zero)

typedef _Float16 f16x8 __attribute__((ext_vector_type(8)));
typedef _Float16 f16x4 __attribute__((ext_vector_type(4)));
typedef float    fx4   __attribute__((ext_vector_type(4)));

#define MFMA16(a, b, c) __builtin_amdgcn_mfma_f32_16x16x32_f16((a), (b), (c), 0, 0, 0)

// ---------------------------------------------------------------- prep 1
__global__ __launch_bounds__(256) void prep_mean(
    const float* __restrict__ w1, const float* __restrict__ w2,
    const float* __restrict__ w3, double* __restrict__ sums) {
  __shared__ double red[256];
  const int b = blockIdx.x;
  const float* w; int n, nb, bb, which;
  if (b < 16)      { w = w1; n = 128 * 784; nb = 16; bb = b;      which = 0; }
  else if (b < 18) { w = w2; n = 64 * 128;  nb = 2;  bb = b - 16; which = 1; }
  else             { w = w3; n = 10 * 64;   nb = 1;  bb = 0;      which = 2; }
  double s = 0.0;
  for (int i = bb * 256 + (int)threadIdx.x; i < n; i += nb * 256)
    s += (double)fabsf(w[i]);
  red[threadIdx.x] = s;
  __syncthreads();
  for (int off = 128; off > 0; off >>= 1) {
    if ((int)threadIdx.x < off) red[threadIdx.x] += red[threadIdx.x + off];
    __syncthreads();
  }
  if (threadIdx.x == 0) atomicAdd(&sums[which], red[0]);
}

// ---------------------------------------------------------------- prep 2
__global__ __launch_bounds__(256) void prep_quant(
    const float* __restrict__ w1, const float* __restrict__ w2,
    const float* __restrict__ w3, const double* __restrict__ sums,
    _Float16* __restrict__ t1, _Float16* __restrict__ t2,
    _Float16* __restrict__ t3) {
  const int idx = blockIdx.x * 256 + (int)threadIdx.x;
  const float s1 = 1.0f / fmaxf((float)(sums[0] * (1.0 / (128.0 * 784.0))), 1e-5f);
  const float s2 = 1.0f / fmaxf((float)(sums[1] * (1.0 / (64.0 * 128.0))), 1e-5f);
  const float s3 = 1.0f / fmaxf((float)(sums[2] * (1.0 / (10.0 * 64.0))), 1e-5f);
  if (idx < 128 * 832) {
    const int n = idx / 832, k = idx - n * 832;
    float v = 0.f;
    if (k < 784) v = fminf(fmaxf(rintf(w1[n * 784 + k] * s1), -1.f), 1.f);
    t1[idx] = (_Float16)v;
  } else if (idx < 128 * 832 + 64 * 128) {
    const int i = idx - 128 * 832;
    t2[i] = (_Float16)fminf(fmaxf(rintf(w2[i] * s2), -1.f), 1.f);
  } else if (idx < 128 * 832 + 64 * 128 + 16 * 64) {
    const int i = idx - (128 * 832 + 64 * 128);
    const int n = i >> 6, k = i & 63;
    float v = 0.f;
    if (n < 10) v = fminf(fmaxf(rintf(w3[n * 64 + k] * s3), -1.f), 1.f);
    t3[i] = (_Float16)v;
  }
}

// ---------------------------------------------------------------- main
// 16 tokens per 256-thread block. Lane roles: wv=wave, g=quad(l>>4), sl=l&15.
// Quant phases: token = wv*4+g, 16 lanes (sl) per token.
// MFMA A-frag: A[m=sl][k=32*kk + 8*g + j]; C/D: D[row=4*g+r][col=sl].
__global__ __launch_bounds__(256, 3) void ffn_main(
    const float* __restrict__ x,
    const float* __restrict__ sc1, const float* __restrict__ sc2,
    const float* __restrict__ sc3,
    const _Float16* __restrict__ t1, const _Float16* __restrict__ t2,
    const _Float16* __restrict__ t3,
    const double* __restrict__ sums,
    float* __restrict__ out) {
  __shared__ _Float16 q1[16 * 840];   // 16 tokens x 832(pad 840) fp16 int-quant
  __shared__ float    h1[16 * 132];   // 16 x 128 (pad 132) fp32
  __shared__ _Float16 q2[16 * 136];   // 16 x 128 (pad 136)
  __shared__ float    h2[16 * 68];    // 16 x 64 (pad 68)
  __shared__ _Float16 q3[16 * 72];    // 16 x 64 (pad 72, keeps 16B align)
  __shared__ float    inv1[16], inv2[16], inv3[16];

  const int tid = threadIdx.x;
  const int l   = tid & 63;
  const int wv  = tid >> 6;
  const int g   = l >> 4;
  const int sl  = l & 15;
  const int token = wv * 4 + g;
  const long tok0 = (long)blockIdx.x * 16;

  const float m1 = fmaxf((float)(sums[0] * (1.0 / (128.0 * 784.0))), 1e-5f);
  const float m2 = fmaxf((float)(sums[1] * (1.0 / (64.0 * 128.0))), 1e-5f);
  const float m3 = fmaxf((float)(sums[2] * (1.0 / (10.0 * 64.0))), 1e-5f);

  // zero q1's K-pad region [784,832) so MFMA sees clean zeros (B pad is also
  // zero, but garbage fp16 here could be NaN and NaN*0 = NaN).
  if (tid < 192) {
    const int t = tid / 12, c = tid - (tid / 12) * 12;
    f16x4 z = {(_Float16)0, (_Float16)0, (_Float16)0, (_Float16)0};
    *reinterpret_cast<f16x4*>(&q1[t * 840 + 784 + c * 4]) = z;
  }

  // ---- layer-1 activation pass 1: row -> regs, sumsq + max|scale*x| ----
  const float* xrow = x + (tok0 + token) * 784;
  fx4 xv[13];
#pragma unroll
  for (int c = 0; c < 12; ++c)
    xv[c] = *reinterpret_cast<const fx4*>(xrow + (sl + 16 * c) * 4);
  if (sl < 4) xv[12] = *reinterpret_cast<const fx4*>(xrow + (sl + 192) * 4);

  float ss = 0.f, am = 0.f;
#pragma unroll
  for (int c = 0; c < 12; ++c) {
    fx4 v = xv[c];
    fx4 s4 = *reinterpret_cast<const fx4*>(sc1 + (sl + 16 * c) * 4);
    ss += v[0] * v[0] + v[1] * v[1] + v[2] * v[2] + v[3] * v[3];
    am = fmaxf(am, fmaxf(fmaxf(fabsf(v[0] * s4[0]), fabsf(v[1] * s4[1])),
                         fmaxf(fabsf(v[2] * s4[2]), fabsf(v[3] * s4[3]))));
  }
  if (sl < 4) {
    fx4 v = xv[12];
    fx4 s4 = *reinterpret_cast<const fx4*>(sc1 + (sl + 192) * 4);
    ss += v[0] * v[0] + v[1] * v[1] + v[2] * v[2] + v[3] * v[3];
    am = fmaxf(am, fmaxf(fmaxf(fabsf(v[0] * s4[0]), fabsf(v[1] * s4[1])),
                         fmaxf(fabsf(v[2] * s4[2]), fabsf(v[3] * s4[3]))));
  }
#pragma unroll
  for (int m = 1; m < 16; m <<= 1) {
    ss += __shfl_xor(ss, m, 64);
    am = fmaxf(am, __shfl_xor(am, m, 64));
  }
  // rms = ||x||/sqrt(784); max|y| = max|scale*x|/(rms+eps)
  const float denom = sqrtf(ss) * (1.0f / 28.0f) + 1e-8f;
  const float invd  = 1.0f / denom;
  const float cl    = fmaxf(am * invd, 1e-5f);
  const float gq    = (127.0f / cl) * invd;
  if (sl == 0) inv1[token] = cl * (1.0f / 127.0f);

  // ---- pass 2: quantize from regs into LDS A-layout ----
#pragma unroll
  for (int c = 0; c < 12; ++c) {
    fx4 v = xv[c];
    fx4 s4 = *reinterpret_cast<const fx4*>(sc1 + (sl + 16 * c) * 4);
    f16x4 q;
    q[0] = (_Float16)fminf(fmaxf(rintf(v[0] * s4[0] * gq), -128.f), 127.f);
    q[1] = (_Float16)fminf(fmaxf(rintf(v[1] * s4[1] * gq), -128.f), 127.f);
    q[2] = (_Float16)fminf(fmaxf(rintf(v[2] * s4[2] * gq), -128.f), 127.f);
    q[3] = (_Float16)fminf(fmaxf(rintf(v[3] * s4[3] * gq), -128.f), 127.f);
    *reinterpret_cast<f16x4*>(&q1[token * 840 + (sl + 16 * c) * 4]) = q;
  }
  if (sl < 4) {
    fx4 v = xv[12];
    fx4 s4 = *reinterpret_cast<const fx4*>(sc1 + (sl + 192) * 4);
    f16x4 q;
    q[0] = (_Float16)fminf(fmaxf(rintf(v[0] * s4[0] * gq), -128.f), 127.f);
    q[1] = (_Float16)fminf(fmaxf(rintf(v[1] * s4[1] * gq), -128.f), 127.f);
    q[2] = (_Float16)fminf(fmaxf(rintf(v[2] * s4[2] * gq), -128.f), 127.f);
    q[3] = (_Float16)fminf(fmaxf(rintf(v[3] * s4[3] * gq), -128.f), 127.f);
    *reinterpret_cast<f16x4*>(&q1[token * 840 + (sl + 192) * 4]) = q;
  }
  __syncthreads();

  // ---- layer-1 MFMA: M=16, N=128 (wave wv -> n-tiles 2wv,2wv+1), K=832 ----
  fx4 acc0 = {0.f, 0.f, 0.f, 0.f}, acc1 = {0.f, 0.f, 0.f, 0.f};
  {
    const _Float16* b0p = t1 + (wv * 32 + sl) * 832;
    const _Float16* b1p = b0p + 16 * 832;
#pragma unroll 2
    for (int kk = 0; kk < 26; ++kk) {
      const int k0 = kk * 32 + g * 8;
      f16x8 a  = *reinterpret_cast<const f16x8*>(&q1[sl * 840 + k0]);
      f16x8 b0 = *reinterpret_cast<const f16x8*>(b0p + k0);
      f16x8 b1 = *reinterpret_cast<const f16x8*>(b1p + k0);
      acc0 = MFMA16(a, b0, acc0);
      acc1 = MFMA16(a, b1, acc1);
    }
  }
#pragma unroll
  for (int r = 0; r < 4; ++r) {
    const int tr = g * 4 + r;
    const float s = inv1[tr] * m1;
    h1[tr * 132 + wv * 32 + sl]      = fmaxf(acc0[r] * s, 0.f);
    h1[tr * 132 + wv * 32 + 16 + sl] = fmaxf(acc1[r] * s, 0.f);
  }
  __syncthreads();

  // ---- layer-2 quant: 128 elems/token, 8 per lane ----
  {
    fx4 v0 = *reinterpret_cast<const fx4*>(&h1[token * 132 + sl * 4]);
    fx4 v1 = *reinterpret_cast<const fx4*>(&h1[token * 132 + 64 + sl * 4]);
    fx4 s0 = *reinterpret_cast<const fx4*>(sc2 + sl * 4);
    fx4 s1 = *reinterpret_cast<const fx4*>(sc2 + 64 + sl * 4);
    float ss2 = v0[0]*v0[0] + v0[1]*v0[1] + v0[2]*v0[2] + v0[3]*v0[3]
              + v1[0]*v1[0] + v1[1]*v1[1] + v1[2]*v1[2] + v1[3]*v1[3];
    float am2 = fmaxf(fmaxf(fmaxf(fabsf(v0[0]*s0[0]), fabsf(v0[1]*s0[1])),
                            fmaxf(fabsf(v0[2]*s0[2]), fabsf(v0[3]*s0[3]))),
                      fmaxf(fmaxf(fabsf(v1[0]*s1[0]), fabsf(v1[1]*s1[1])),
                            fmaxf(fabsf(v1[2]*s1[2]), fabsf(v1[3]*s1[3]))));
#pragma unroll
    for (int m = 1; m < 16; m <<= 1) {
      ss2 += __shfl_xor(ss2, m, 64);
      am2 = fmaxf(am2, __shfl_xor(am2, m, 64));
    }
    const float den2 = sqrtf(ss2) * 0.08838834764831845f + 1e-8f; // 1/sqrt(128)
    const float id2  = 1.0f / den2;
    const float cl2  = fmaxf(am2 * id2, 1e-5f);
    const float gq2  = (127.0f / cl2) * id2;
    if (sl == 0) inv2[token] = cl2 * (1.0f / 127.0f);
    f16x4 qa, qb;
    qa[0] = (_Float16)fminf(fmaxf(rintf(v0[0]*s0[0]*gq2), -128.f), 127.f);
    qa[1] = (_Float16)fminf(fmaxf(rintf(v0[1]*s0[1]*gq2), -128.f), 127.f);
    qa[2] = (_Float16)fminf(fmaxf(rintf(v0[2]*s0[2]*gq2), -128.f), 127.f);
    qa[3] = (_Float16)fminf(fmaxf(rintf(v0[3]*s0[3]*gq2), -128.f), 127.f);
    qb[0] = (_Float16)fminf(fmaxf(rintf(v1[0]*s1[0]*gq2), -128.f), 127.f);
    qb[1] = (_Float16)fminf(fmaxf(rintf(v1[1]*s1[1]*gq2), -128.f), 127.f);
    qb[2] = (_Float16)fminf(fmaxf(rintf(v1[2]*s1[2]*gq2), -128.f), 127.f);
    qb[3] = (_Float16)fminf(fmaxf(rintf(v1[3]*s1[3]*gq2), -128.f), 127.f);
    *reinterpret_cast<f16x4*>(&q2[token * 136 + sl * 4]) = qa;
    *reinterpret_cast<f16x4*>(&q2[token * 136 + 64 + sl * 4]) = qb;
  }
  __syncthreads();

  // ---- layer-2 MFMA: M=16, N=64 (wave wv -> n-tile wv), K=128 ----
  fx4 acc2 = {0.f, 0.f, 0.f, 0.f};
  {
    const _Float16* bp = t2 + (wv * 16 + sl) * 128;
#pragma unroll
    for (int kk = 0; kk < 4; ++kk) {
      const int k0 = kk * 32 + g * 8;
      f16x8 a = *reinterpret_cast<const f16x8*>(&q2[sl * 136 + k0]);
      f16x8 b = *reinterpret_cast<const f16x8*>(bp + k0);
      acc2 = MFMA16(a, b, acc2);
    }
  }
#pragma unroll
  for (int r = 0; r < 4; ++r) {
    const int tr = g * 4 + r;
    h2[tr * 68 + wv * 16 + sl] = fmaxf(acc2[r] * inv2[tr] * m2, 0.f);
  }
  __syncthreads();

  // ---- layer-3 quant: 64 elems/token, 4 per lane ----
  {
    fx4 v = *reinterpret_cast<const fx4*>(&h2[token * 68 + sl * 4]);
    fx4 s = *reinterpret_cast<const fx4*>(sc3 + sl * 4);
    float ss3 = v[0]*v[0] + v[1]*v[1] + v[2]*v[2] + v[3]*v[3];
    float am3 = fmaxf(fmaxf(fabsf(v[0]*s[0]), fabsf(v[1]*s[1])),
                      fmaxf(fabsf(v[2]*s[2]), fabsf(v[3]*s[3])));
#pragma unroll
    for (int m = 1; m < 16; m <<= 1) {
      ss3 += __shfl_xor(ss3, m, 64);
      am3 = fmaxf(am3, __shfl_xor(am3, m, 64));
    }
    const float den3 = sqrtf(ss3) * 0.125f + 1e-8f;  // 1/sqrt(64)
    const float id3  = 1.0f / den3;
    const float cl3  = fmaxf(am3 * id3, 1e-5f);
    const float gq3  = (127.0f / cl3) * id3;
    if (sl == 0) inv3[token] = cl3 * (1.0f / 127.0f);
    f16x4 q;
    q[0] = (_Float16)fminf(fmaxf(rintf(v[0]*s[0]*gq3), -128.f), 127.f);
    q[1] = (_Float16)fminf(fmaxf(rintf(v[1]*s[1]*gq3), -128.f), 127.f);
    q[2] = (_Float16)fminf(fmaxf(rintf(v[2]*s[2]*gq3), -128.f), 127.f);
    q[3] = (_Float16)fminf(fmaxf(rintf(v[3]*s[3]*gq3), -128.f), 127.f);
    *reinterpret_cast<f16x4*>(&q3[token * 72 + sl * 4]) = q;
  }
  __syncthreads();

  // ---- layer-3 MFMA: M=16, N=16(10), K=64 — wave 0 only ----
  if (wv == 0) {
    fx4 acc3 = {0.f, 0.f, 0.f, 0.f};
#pragma unroll
    for (int kk = 0; kk < 2; ++kk) {
      const int k0 = kk * 32 + g * 8;
      f16x8 a = *reinterpret_cast<const f16x8*>(&q3[sl * 72 + k0]);
      f16x8 b = *reinterpret_cast<const f16x8*>(t3 + sl * 64 + k0);
      acc3 = MFMA16(a, b, acc3);
    }
    if (sl < 10) {
#pragma unroll
      for (int r = 0; r < 4; ++r) {
        const int tr = g * 4 + r;
        out[(tok0 + tr) * 10 + sl] = acc3[r] * inv3[tr] * m3;
      }
    }
  }
}

// ---------------------------------------------------------------- launch
extern "C" void kernel_launch(void* const* d_in, const int* in_sizes, int n_in,
                              void* d_out, int out_size, void* d_ws, size_t ws_size,
                              hipStream_t stream) {
  const float* x  = (const float*)d_in[0];
  const float* w1 = (const float*)d_in[1];
  const float* s1 = (const float*)d_in[2];
  const float* w2 = (const float*)d_in[3];
  const float* s2 = (const float*)d_in[4];
  const float* w3 = (const float*)d_in[5];
  const float* s3 = (const float*)d_in[6];
  float* out = (float*)d_out;

  char* ws = (char*)d_ws;
  double*   sums = (double*)ws;
  _Float16* t1 = (_Float16*)(ws + 256);
  _Float16* t2 = (_Float16*)(ws + 213248);
  _Float16* t3 = (_Float16*)(ws + 229632);

  const int B = in_sizes[0] / 784;

  hipMemsetAsync(sums, 0, 3 * sizeof(double), stream);
  prep_mean<<<19, 256, 0, stream>>>(w1, w2, w3, sums);
  const int total_q = 128 * 832 + 64 * 128 + 16 * 64;  // 115712
  prep_quant<<<(total_q + 255) / 256, 256, 0, stream>>>(w1, w2, w3, sums, t1, t2, t3);
  ffn_main<<<B / 16, 256, 0, stream>>>(x, s1, s2, s3, t1, t2, t3, sums, out);
}

// Round 2
// 373.313 us; speedup vs baseline: 1.0771x; 1.0771x over previous
//
#include <hip/hip_runtime.h>
#include <stdint.h>

// BitNet-style fused 3-layer MLP for MI355X (gfx950) — round 2.
//
// Round-1 post-mortem: latency-bound (MfmaUtil 3%, VALU 13%, occ 30%).
// Changes: (1) persistent blocks (grid=1024, 4/CU) with register prefetch of
// the next token-tile's x across barriers; (2) barriers are raw s_barrier +
// lgkmcnt(0) only (CK block_sync_lds pattern) so prefetch global loads stay
// in flight; (3) int8 MFMA (mfma_i32_16x16x64_i8) — activations are integers
// in [-128,127], weights ternary, so int32 accumulation is bit-exact, LDS
// and weight L2 traffic halve vs fp16.
//
// ws layout:
//   [0,24)    double sums[3] (Σ|w| per tensor; zeroed via hipMemsetAsync)
//   256       t1: 128 x 832 int8 ternary w1 (K padded 784->832 w/ zeros)
//   106752    t2: 64 x 128 int8 ternary w2
//   114944    t3: 16 x 64  int8 ternary w3 (rows 10..15 zero)

typedef int   ix4 __attribute__((ext_vector_type(4)));
typedef float fx4 __attribute__((ext_vector_type(4)));

#define MFMA_I8(a, b, c) __builtin_amdgcn_mfma_i32_16x16x64_i8((a), (b), (c), 0, 0, 0)

// CK-style barrier: waits LDS ops only; global register loads stay in flight.
__device__ __forceinline__ void sync_lds() {
  asm volatile("s_waitcnt lgkmcnt(0)" ::: "memory");
  __builtin_amdgcn_s_barrier();
}

// ---------------------------------------------------------------- prep 1
__global__ __launch_bounds__(256) void prep_mean(
    const float* __restrict__ w1, const float* __restrict__ w2,
    const float* __restrict__ w3, double* __restrict__ sums) {
  __shared__ double red[256];
  const int b = blockIdx.x;
  const float* w; int n, nb, bb, which;
  if (b < 240)      { w = w1; n = 128 * 784; nb = 240; bb = b;       which = 0; }
  else if (b < 248) { w = w2; n = 64 * 128;  nb = 8;   bb = b - 240; which = 1; }
  else              { w = w3; n = 10 * 64;   nb = 1;   bb = 0;       which = 2; }
  double s = 0.0;
  for (int i = bb * 256 + (int)threadIdx.x; i < n; i += nb * 256)
    s += (double)fabsf(w[i]);
  red[threadIdx.x] = s;
  __syncthreads();
  for (int off = 128; off > 0; off >>= 1) {
    if ((int)threadIdx.x < off) red[threadIdx.x] += red[threadIdx.x + off];
    __syncthreads();
  }
  if (threadIdx.x == 0) atomicAdd(&sums[which], red[0]);
}

// ---------------------------------------------------------------- prep 2
__global__ __launch_bounds__(256) void prep_quant(
    const float* __restrict__ w1, const float* __restrict__ w2,
    const float* __restrict__ w3, const double* __restrict__ sums,
    int8_t* __restrict__ t1, int8_t* __restrict__ t2,
    int8_t* __restrict__ t3) {
  const int idx = blockIdx.x * 256 + (int)threadIdx.x;
  const float s1 = 1.0f / fmaxf((float)(sums[0] * (1.0 / (128.0 * 784.0))), 1e-5f);
  const float s2 = 1.0f / fmaxf((float)(sums[1] * (1.0 / (64.0 * 128.0))), 1e-5f);
  const float s3 = 1.0f / fmaxf((float)(sums[2] * (1.0 / (10.0 * 64.0))), 1e-5f);
  if (idx < 128 * 832) {
    const int n = idx / 832, k = idx - n * 832;
    float v = 0.f;
    if (k < 784) v = fminf(fmaxf(rintf(w1[n * 784 + k] * s1), -1.f), 1.f);
    t1[idx] = (int8_t)(int)v;
  } else if (idx < 128 * 832 + 64 * 128) {
    const int i = idx - 128 * 832;
    t2[i] = (int8_t)(int)fminf(fmaxf(rintf(w2[i] * s2), -1.f), 1.f);
  } else if (idx < 128 * 832 + 64 * 128 + 16 * 64) {
    const int i = idx - (128 * 832 + 64 * 128);
    const int n = i >> 6, k = i & 63;
    float v = 0.f;
    if (n < 10) v = fminf(fmaxf(rintf(w3[n * 64 + k] * s3), -1.f), 1.f);
    t3[i] = (int8_t)(int)v;
  }
}

// ---------------------------------------------------------------- main
// Persistent blocks; 16 tokens per tile; tile = blockIdx + it*gridDim.
// Lane roles: wv=wave, g=quad(l>>4), sl=l&15; quant token = wv*4+g.
// i8 MFMA A-frag: A[m=sl][k=64*kk + 16*g + j], j=0..15; C/D: D[4g+r][sl].
__global__ __launch_bounds__(256, 4) void ffn_main(
    const float* __restrict__ x,
    const float* __restrict__ sc1, const float* __restrict__ sc2,
    const float* __restrict__ sc3,
    const int8_t* __restrict__ t1, const int8_t* __restrict__ t2,
    const int8_t* __restrict__ t3,
    const double* __restrict__ sums,
    float* __restrict__ out, int numTiles) {
  __shared__ int8_t q1[16 * 848];   // 16 tokens x 832(pad 848) int8
  __shared__ float  h1[16 * 132];   // 16 x 128 (pad 132) fp32
  __shared__ int8_t q2[16 * 144];   // 16 x 128 (pad 144)
  __shared__ float  h2[16 * 68];    // 16 x 64 (pad 68)
  __shared__ int8_t q3[16 * 80];    // 16 x 64 (pad 80)
  __shared__ float  inv1[16], inv2[16], inv3[16];

  const int tid = threadIdx.x;
  const int l   = tid & 63;
  const int wv  = tid >> 6;
  const int g   = l >> 4;
  const int sl  = l & 15;
  const int token = wv * 4 + g;

  const float m1 = fmaxf((float)(sums[0] * (1.0 / (128.0 * 784.0))), 1e-5f);
  const float m2 = fmaxf((float)(sums[1] * (1.0 / (64.0 * 128.0))), 1e-5f);
  const float m3 = fmaxf((float)(sums[2] * (1.0 / (10.0 * 64.0))), 1e-5f);

  // zero q1's K-pad [784,832) once (never overwritten afterwards)
  if (tid < 192) {
    const int t = tid / 12, c = tid - (tid / 12) * 12;
    *reinterpret_cast<unsigned*>(&q1[t * 848 + 784 + c * 4]) = 0u;
  }

  fx4 xv[13];
  int tile = blockIdx.x;
  if (tile < numTiles) {
    const float* rowp = x + (size_t)(tile * 16 + token) * 784;
#pragma unroll
    for (int c = 0; c < 12; ++c)
      xv[c] = *reinterpret_cast<const fx4*>(rowp + (sl + 16 * c) * 4);
    if (sl < 4) xv[12] = *reinterpret_cast<const fx4*>(rowp + (sl + 192) * 4);
  }

  for (; tile < numTiles; tile += (int)gridDim.x) {
    // ---- layer-1 stats: sumsq + max|scale*x| over the 784-row ----
    float ss = 0.f, am = 0.f;
#pragma unroll
    for (int c = 0; c < 12; ++c) {
      fx4 v = xv[c];
      fx4 s4 = *reinterpret_cast<const fx4*>(sc1 + (sl + 16 * c) * 4);
      ss += v[0] * v[0] + v[1] * v[1] + v[2] * v[2] + v[3] * v[3];
      am = fmaxf(am, fmaxf(fmaxf(fabsf(v[0] * s4[0]), fabsf(v[1] * s4[1])),
                           fmaxf(fabsf(v[2] * s4[2]), fabsf(v[3] * s4[3]))));
    }
    if (sl < 4) {
      fx4 v = xv[12];
      fx4 s4 = *reinterpret_cast<const fx4*>(sc1 + (sl + 192) * 4);
      ss += v[0] * v[0] + v[1] * v[1] + v[2] * v[2] + v[3] * v[3];
      am = fmaxf(am, fmaxf(fmaxf(fabsf(v[0] * s4[0]), fabsf(v[1] * s4[1])),
                           fmaxf(fabsf(v[2] * s4[2]), fabsf(v[3] * s4[3]))));
    }
#pragma unroll
    for (int m = 1; m < 16; m <<= 1) {
      ss += __shfl_xor(ss, m, 64);
      am = fmaxf(am, __shfl_xor(am, m, 64));
    }
    const float denom = sqrtf(ss) * (1.0f / 28.0f) + 1e-8f;  // rms + eps
    const float invd  = 1.0f / denom;
    const float cl    = fmaxf(am * invd, 1e-5f);
    const float gq    = (127.0f / cl) * invd;
    if (sl == 0) inv1[token] = cl * (1.0f / 127.0f);

    // ---- quantize from regs into LDS (packed int8) ----
#pragma unroll
    for (int c = 0; c < 12; ++c) {
      fx4 v = xv[c];
      fx4 s4 = *reinterpret_cast<const fx4*>(sc1 + (sl + 16 * c) * 4);
      int q0 = (int)fminf(fmaxf(rintf(v[0] * s4[0] * gq), -128.f), 127.f);
      int q1i = (int)fminf(fmaxf(rintf(v[1] * s4[1] * gq), -128.f), 127.f);
      int q2i = (int)fminf(fmaxf(rintf(v[2] * s4[2] * gq), -128.f), 127.f);
      int q3i = (int)fminf(fmaxf(rintf(v[3] * s4[3] * gq), -128.f), 127.f);
      unsigned p = (unsigned)(q0 & 255) | ((unsigned)(q1i & 255) << 8) |
                   ((unsigned)(q2i & 255) << 16) | ((unsigned)(q3i & 255) << 24);
      *reinterpret_cast<unsigned*>(&q1[token * 848 + (sl + 16 * c) * 4]) = p;
    }
    if (sl < 4) {
      fx4 v = xv[12];
      fx4 s4 = *reinterpret_cast<const fx4*>(sc1 + (sl + 192) * 4);
      int q0 = (int)fminf(fmaxf(rintf(v[0] * s4[0] * gq), -128.f), 127.f);
      int q1i = (int)fminf(fmaxf(rintf(v[1] * s4[1] * gq), -128.f), 127.f);
      int q2i = (int)fminf(fmaxf(rintf(v[2] * s4[2] * gq), -128.f), 127.f);
      int q3i = (int)fminf(fmaxf(rintf(v[3] * s4[3] * gq), -128.f), 127.f);
      unsigned p = (unsigned)(q0 & 255) | ((unsigned)(q1i & 255) << 8) |
                   ((unsigned)(q2i & 255) << 16) | ((unsigned)(q3i & 255) << 24);
      *reinterpret_cast<unsigned*>(&q1[token * 848 + (sl + 192) * 4]) = p;
    }

    // ---- prefetch next tile's x into the now-dead registers ----
    {
      const int ntile = tile + (int)gridDim.x;
      const int ptile = (ntile < numTiles) ? ntile : tile;  // dummy re-read on last iter
      const float* rowp = x + (size_t)(ptile * 16 + token) * 784;
#pragma unroll
      for (int c = 0; c < 12; ++c)
        xv[c] = *reinterpret_cast<const fx4*>(rowp + (sl + 16 * c) * 4);
      if (sl < 4) xv[12] = *reinterpret_cast<const fx4*>(rowp + (sl + 192) * 4);
    }

    sync_lds();  // q1 ready (prefetch loads stay in flight)

    // ---- layer-1 MFMA: M=16, N=128 (wave wv -> cols wv*32..+31), K=832 ----
    ix4 acc0 = {0, 0, 0, 0}, acc1 = {0, 0, 0, 0};
    {
      const int8_t* b0p = t1 + (wv * 32 + sl) * 832;
      const int8_t* b1p = b0p + 16 * 832;
#pragma unroll 4
      for (int kk = 0; kk < 13; ++kk) {
        const int k0 = kk * 64 + g * 16;
        ix4 a  = *reinterpret_cast<const ix4*>(&q1[sl * 848 + k0]);
        ix4 b0 = *reinterpret_cast<const ix4*>(b0p + k0);
        ix4 b1 = *reinterpret_cast<const ix4*>(b1p + k0);
        acc0 = MFMA_I8(a, b0, acc0);
        acc1 = MFMA_I8(a, b1, acc1);
      }
    }
#pragma unroll
    for (int r = 0; r < 4; ++r) {
      const int tr = g * 4 + r;
      const float s = inv1[tr] * m1;
      h1[tr * 132 + wv * 32 + sl]      = fmaxf((float)acc0[r] * s, 0.f);
      h1[tr * 132 + wv * 32 + 16 + sl] = fmaxf((float)acc1[r] * s, 0.f);
    }
    sync_lds();  // h1 ready

    // ---- layer-2 quant: 128 elems/token, 8 per lane ----
    {
      fx4 v0 = *reinterpret_cast<const fx4*>(&h1[token * 132 + sl * 4]);
      fx4 v1 = *reinterpret_cast<const fx4*>(&h1[token * 132 + 64 + sl * 4]);
      fx4 s0 = *reinterpret_cast<const fx4*>(sc2 + sl * 4);
      fx4 s1 = *reinterpret_cast<const fx4*>(sc2 + 64 + sl * 4);
      float ss2 = v0[0]*v0[0] + v0[1]*v0[1] + v0[2]*v0[2] + v0[3]*v0[3]
                + v1[0]*v1[0] + v1[1]*v1[1] + v1[2]*v1[2] + v1[3]*v1[3];
      float am2 = fmaxf(fmaxf(fmaxf(fabsf(v0[0]*s0[0]), fabsf(v0[1]*s0[1])),
                              fmaxf(fabsf(v0[2]*s0[2]), fabsf(v0[3]*s0[3]))),
                        fmaxf(fmaxf(fabsf(v1[0]*s1[0]), fabsf(v1[1]*s1[1])),
                              fmaxf(fabsf(v1[2]*s1[2]), fabsf(v1[3]*s1[3]))));
#pragma unroll
      for (int m = 1; m < 16; m <<= 1) {
        ss2 += __shfl_xor(ss2, m, 64);
        am2 = fmaxf(am2, __shfl_xor(am2, m, 64));
      }
      const float den2 = sqrtf(ss2) * 0.08838834764831845f + 1e-8f; // 1/sqrt(128)
      const float id2  = 1.0f / den2;
      const float cl2  = fmaxf(am2 * id2, 1e-5f);
      const float gq2  = (127.0f / cl2) * id2;
      if (sl == 0) inv2[token] = cl2 * (1.0f / 127.0f);
      int a0 = (int)fminf(fmaxf(rintf(v0[0]*s0[0]*gq2), -128.f), 127.f);
      int a1 = (int)fminf(fmaxf(rintf(v0[1]*s0[1]*gq2), -128.f), 127.f);
      int a2 = (int)fminf(fmaxf(rintf(v0[2]*s0[2]*gq2), -128.f), 127.f);
      int a3 = (int)fminf(fmaxf(rintf(v0[3]*s0[3]*gq2), -128.f), 127.f);
      int b0 = (int)fminf(fmaxf(rintf(v1[0]*s1[0]*gq2), -128.f), 127.f);
      int b1 = (int)fminf(fmaxf(rintf(v1[1]*s1[1]*gq2), -128.f), 127.f);
      int b2 = (int)fminf(fmaxf(rintf(v1[2]*s1[2]*gq2), -128.f), 127.f);
      int b3 = (int)fminf(fmaxf(rintf(v1[3]*s1[3]*gq2), -128.f), 127.f);
      unsigned pa = (unsigned)(a0 & 255) | ((unsigned)(a1 & 255) << 8) |
                    ((unsigned)(a2 & 255) << 16) | ((unsigned)(a3 & 255) << 24);
      unsigned pb = (unsigned)(b0 & 255) | ((unsigned)(b1 & 255) << 8) |
                    ((unsigned)(b2 & 255) << 16) | ((unsigned)(b3 & 255) << 24);
      *reinterpret_cast<unsigned*>(&q2[token * 144 + sl * 4]) = pa;
      *reinterpret_cast<unsigned*>(&q2[token * 144 + 64 + sl * 4]) = pb;
    }
    sync_lds();  // q2 ready

    // ---- layer-2 MFMA: M=16, N=64 (wave wv -> cols wv*16..+15), K=128 ----
    ix4 acc2 = {0, 0, 0, 0};
    {
      const int8_t* bp = t2 + (wv * 16 + sl) * 128;
#pragma unroll
      for (int kk = 0; kk < 2; ++kk) {
        const int k0 = kk * 64 + g * 16;
        ix4 a = *reinterpret_cast<const ix4*>(&q2[sl * 144 + k0]);
        ix4 b = *reinterpret_cast<const ix4*>(bp + k0);
        acc2 = MFMA_I8(a, b, acc2);
      }
    }
#pragma unroll
    for (int r = 0; r < 4; ++r) {
      const int tr = g * 4 + r;
      h2[tr * 68 + wv * 16 + sl] = fmaxf((float)acc2[r] * inv2[tr] * m2, 0.f);
    }
    sync_lds();  // h2 ready

    // ---- layer-3 quant: 64 elems/token, 4 per lane ----
    {
      fx4 v = *reinterpret_cast<const fx4*>(&h2[token * 68 + sl * 4]);
      fx4 s = *reinterpret_cast<const fx4*>(sc3 + sl * 4);
      float ss3 = v[0]*v[0] + v[1]*v[1] + v[2]*v[2] + v[3]*v[3];
      float am3 = fmaxf(fmaxf(fabsf(v[0]*s[0]), fabsf(v[1]*s[1])),
                        fmaxf(fabsf(v[2]*s[2]), fabsf(v[3]*s[3])));
#pragma unroll
      for (int m = 1; m < 16; m <<= 1) {
        ss3 += __shfl_xor(ss3, m, 64);
        am3 = fmaxf(am3, __shfl_xor(am3, m, 64));
      }
      const float den3 = sqrtf(ss3) * 0.125f + 1e-8f;  // 1/sqrt(64)
      const float id3  = 1.0f / den3;
      const float cl3  = fmaxf(am3 * id3, 1e-5f);
      const float gq3  = (127.0f / cl3) * id3;
      if (sl == 0) inv3[token] = cl3 * (1.0f / 127.0f);
      int c0 = (int)fminf(fmaxf(rintf(v[0]*s[0]*gq3), -128.f), 127.f);
      int c1 = (int)fminf(fmaxf(rintf(v[1]*s[1]*gq3), -128.f), 127.f);
      int c2 = (int)fminf(fmaxf(rintf(v[2]*s[2]*gq3), -128.f), 127.f);
      int c3 = (int)fminf(fmaxf(rintf(v[3]*s[3]*gq3), -128.f), 127.f);
      unsigned p = (unsigned)(c0 & 255) | ((unsigned)(c1 & 255) << 8) |
                   ((unsigned)(c2 & 255) << 16) | ((unsigned)(c3 & 255) << 24);
      *reinterpret_cast<unsigned*>(&q3[token * 80 + sl * 4]) = p;
    }
    sync_lds();  // q3 ready

    // ---- layer-3 MFMA: M=16, N=16(10), K=64 — wave 0 only ----
    if (wv == 0) {
      ix4 acc3 = {0, 0, 0, 0};
      ix4 a = *reinterpret_cast<const ix4*>(&q3[sl * 80 + g * 16]);
      ix4 b = *reinterpret_cast<const ix4*>(t3 + sl * 64 + g * 16);
      acc3 = MFMA_I8(a, b, acc3);
      if (sl < 10) {
        const long tok0 = (long)tile * 16;
#pragma unroll
        for (int r = 0; r < 4; ++r) {
          const int tr = g * 4 + r;
          out[(tok0 + tr) * 10 + sl] = (float)acc3[r] * inv3[tr] * m3;
        }
      }
    }
    sync_lds();  // everyone done with q3/h-buffers before next iter's writes
  }
}

// ---------------------------------------------------------------- launch
extern "C" void kernel_launch(void* const* d_in, const int* in_sizes, int n_in,
                              void* d_out, int out_size, void* d_ws, size_t ws_size,
                              hipStream_t stream) {
  const float* x  = (const float*)d_in[0];
  const float* w1 = (const float*)d_in[1];
  const float* s1 = (const float*)d_in[2];
  const float* w2 = (const float*)d_in[3];
  const float* s2 = (const float*)d_in[4];
  const float* w3 = (const float*)d_in[5];
  const float* s3 = (const float*)d_in[6];
  float* out = (float*)d_out;

  char* ws = (char*)d_ws;
  double* sums = (double*)ws;
  int8_t* t1 = (int8_t*)(ws + 256);
  int8_t* t2 = (int8_t*)(ws + 106752);
  int8_t* t3 = (int8_t*)(ws + 114944);

  const int B = in_sizes[0] / 784;
  const int numTiles = B / 16;

  hipMemsetAsync(sums, 0, 3 * sizeof(double), stream);
  prep_mean<<<249, 256, 0, stream>>>(w1, w2, w3, sums);
  const int total_q = 128 * 832 + 64 * 128 + 16 * 64;  // 115712
  prep_quant<<<(total_q + 255) / 256, 256, 0, stream>>>(w1, w2, w3, sums, t1, t2, t3);
  const int grid = numTiles < 1024 ? numTiles : 1024;
  ffn_main<<<grid, 256, 0, stream>>>(x, s1, s2, s3, t1, t2, t3, sums, out, numTiles);
}

// Round 3
// 319.788 us; speedup vs baseline: 1.2574x; 1.1674x over previous
//
#include <hip/hip_runtime.h>
#include <stdint.h>

// BitNet-style fused 3-layer MLP for MI355X (gfx950) — round 3.
//
// Round-2 post-mortem: launch_bounds(256,4) made the allocator target 8
// waves/EU -> 64 VGPRs -> spilled the xv[13] prefetch array to scratch
// (WRITE_SIZE 70 MB, +50 MB FETCH, prefetch serialized at HBM latency).
// Round-3: amdgpu_waves_per_eu(2,4) gives the allocator a 128-256 VGPR
// budget so the prefetch lives in registers; last-iter dummy prefetch
// removed (was +51 MB fetch).
//
// ws layout:
//   [0,24)    double sums[3] (Σ|w| per tensor; zeroed via hipMemsetAsync)
//   256       t1: 128 x 832 int8 ternary w1 (K padded 784->832 w/ zeros)
//   106752    t2: 64 x 128 int8 ternary w2
//   114944    t3: 16 x 64  int8 ternary w3 (rows 10..15 zero)

typedef int   ix4 __attribute__((ext_vector_type(4)));
typedef float fx4 __attribute__((ext_vector_type(4)));

#define MFMA_I8(a, b, c) __builtin_amdgcn_mfma_i32_16x16x64_i8((a), (b), (c), 0, 0, 0)

// CK-style barrier: waits LDS ops only; global register loads stay in flight.
__device__ __forceinline__ void sync_lds() {
  asm volatile("s_waitcnt lgkmcnt(0)" ::: "memory");
  __builtin_amdgcn_s_barrier();
}

// ---------------------------------------------------------------- prep 1
__global__ __launch_bounds__(256) void prep_mean(
    const float* __restrict__ w1, const float* __restrict__ w2,
    const float* __restrict__ w3, double* __restrict__ sums) {
  __shared__ double red[256];
  const int b = blockIdx.x;
  const float* w; int n, nb, bb, which;
  if (b < 240)      { w = w1; n = 128 * 784; nb = 240; bb = b;       which = 0; }
  else if (b < 248) { w = w2; n = 64 * 128;  nb = 8;   bb = b - 240; which = 1; }
  else              { w = w3; n = 10 * 64;   nb = 1;   bb = 0;       which = 2; }
  double s = 0.0;
  for (int i = bb * 256 + (int)threadIdx.x; i < n; i += nb * 256)
    s += (double)fabsf(w[i]);
  red[threadIdx.x] = s;
  __syncthreads();
  for (int off = 128; off > 0; off >>= 1) {
    if ((int)threadIdx.x < off) red[threadIdx.x] += red[threadIdx.x + off];
    __syncthreads();
  }
  if (threadIdx.x == 0) atomicAdd(&sums[which], red[0]);
}

// ---------------------------------------------------------------- prep 2
__global__ __launch_bounds__(256) void prep_quant(
    const float* __restrict__ w1, const float* __restrict__ w2,
    const float* __restrict__ w3, const double* __restrict__ sums,
    int8_t* __restrict__ t1, int8_t* __restrict__ t2,
    int8_t* __restrict__ t3) {
  const int idx = blockIdx.x * 256 + (int)threadIdx.x;
  const float s1 = 1.0f / fmaxf((float)(sums[0] * (1.0 / (128.0 * 784.0))), 1e-5f);
  const float s2 = 1.0f / fmaxf((float)(sums[1] * (1.0 / (64.0 * 128.0))), 1e-5f);
  const float s3 = 1.0f / fmaxf((float)(sums[2] * (1.0 / (10.0 * 64.0))), 1e-5f);
  if (idx < 128 * 832) {
    const int n = idx / 832, k = idx - n * 832;
    float v = 0.f;
    if (k < 784) v = fminf(fmaxf(rintf(w1[n * 784 + k] * s1), -1.f), 1.f);
    t1[idx] = (int8_t)(int)v;
  } else if (idx < 128 * 832 + 64 * 128) {
    const int i = idx - 128 * 832;
    t2[i] = (int8_t)(int)fminf(fmaxf(rintf(w2[i] * s2), -1.f), 1.f);
  } else if (idx < 128 * 832 + 64 * 128 + 16 * 64) {
    const int i = idx - (128 * 832 + 64 * 128);
    const int n = i >> 6, k = i & 63;
    float v = 0.f;
    if (n < 10) v = fminf(fmaxf(rintf(w3[n * 64 + k] * s3), -1.f), 1.f);
    t3[i] = (int8_t)(int)v;
  }
}

// ---------------------------------------------------------------- main
// Persistent blocks; 16 tokens per tile; tile = blockIdx + it*gridDim.
// Lane roles: wv=wave, g=quad(l>>4), sl=l&15; quant token = wv*4+g.
// i8 MFMA A-frag: A[m=sl][k=64*kk + 16*g + j], j=0..15; C/D: D[4g+r][sl].
__global__ __launch_bounds__(256)
__attribute__((amdgpu_waves_per_eu(2, 4)))
void ffn_main(
    const float* __restrict__ x,
    const float* __restrict__ sc1, const float* __restrict__ sc2,
    const float* __restrict__ sc3,
    const int8_t* __restrict__ t1, const int8_t* __restrict__ t2,
    const int8_t* __restrict__ t3,
    const double* __restrict__ sums,
    float* __restrict__ out, int numTiles) {
  __shared__ int8_t q1[16 * 848];   // 16 tokens x 832(pad 848) int8
  __shared__ float  h1[16 * 132];   // 16 x 128 (pad 132) fp32
  __shared__ int8_t q2[16 * 144];   // 16 x 128 (pad 144)
  __shared__ float  h2[16 * 68];    // 16 x 64 (pad 68)
  __shared__ int8_t q3[16 * 80];    // 16 x 64 (pad 80)
  __shared__ float  inv1[16], inv2[16], inv3[16];

  const int tid = threadIdx.x;
  const int l   = tid & 63;
  const int wv  = tid >> 6;
  const int g   = l >> 4;
  const int sl  = l & 15;
  const int token = wv * 4 + g;

  const float m1 = fmaxf((float)(sums[0] * (1.0 / (128.0 * 784.0))), 1e-5f);
  const float m2 = fmaxf((float)(sums[1] * (1.0 / (64.0 * 128.0))), 1e-5f);
  const float m3 = fmaxf((float)(sums[2] * (1.0 / (10.0 * 64.0))), 1e-5f);

  // zero q1's K-pad [784,832) once (never overwritten afterwards)
  if (tid < 192) {
    const int t = tid / 12, c = tid - (tid / 12) * 12;
    *reinterpret_cast<unsigned*>(&q1[t * 848 + 784 + c * 4]) = 0u;
  }

  fx4 xv[13];
  int tile = blockIdx.x;
  if (tile < numTiles) {
    const float* rowp = x + (size_t)(tile * 16 + token) * 784;
#pragma unroll
    for (int c = 0; c < 12; ++c)
      xv[c] = *reinterpret_cast<const fx4*>(rowp + (sl + 16 * c) * 4);
    if (sl < 4) xv[12] = *reinterpret_cast<const fx4*>(rowp + (sl + 192) * 4);
  }

  for (; tile < numTiles; tile += (int)gridDim.x) {
    // ---- layer-1 stats: sumsq + max|scale*x| over the 784-row ----
    float ss = 0.f, am = 0.f;
#pragma unroll
    for (int c = 0; c < 12; ++c) {
      fx4 v = xv[c];
      fx4 s4 = *reinterpret_cast<const fx4*>(sc1 + (sl + 16 * c) * 4);
      ss += v[0] * v[0] + v[1] * v[1] + v[2] * v[2] + v[3] * v[3];
      am = fmaxf(am, fmaxf(fmaxf(fabsf(v[0] * s4[0]), fabsf(v[1] * s4[1])),
                           fmaxf(fabsf(v[2] * s4[2]), fabsf(v[3] * s4[3]))));
    }
    if (sl < 4) {
      fx4 v = xv[12];
      fx4 s4 = *reinterpret_cast<const fx4*>(sc1 + (sl + 192) * 4);
      ss += v[0] * v[0] + v[1] * v[1] + v[2] * v[2] + v[3] * v[3];
      am = fmaxf(am, fmaxf(fmaxf(fabsf(v[0] * s4[0]), fabsf(v[1] * s4[1])),
                           fmaxf(fabsf(v[2] * s4[2]), fabsf(v[3] * s4[3]))));
    }
#pragma unroll
    for (int m = 1; m < 16; m <<= 1) {
      ss += __shfl_xor(ss, m, 64);
      am = fmaxf(am, __shfl_xor(am, m, 64));
    }
    const float denom = sqrtf(ss) * (1.0f / 28.0f) + 1e-8f;  // rms + eps
    const float invd  = 1.0f / denom;
    const float cl    = fmaxf(am * invd, 1e-5f);
    const float gq    = (127.0f / cl) * invd;
    if (sl == 0) inv1[token] = cl * (1.0f / 127.0f);

    // ---- quantize from regs into LDS (packed int8) ----
#pragma unroll
    for (int c = 0; c < 12; ++c) {
      fx4 v = xv[c];
      fx4 s4 = *reinterpret_cast<const fx4*>(sc1 + (sl + 16 * c) * 4);
      int q0 = (int)fminf(fmaxf(rintf(v[0] * s4[0] * gq), -128.f), 127.f);
      int q1i = (int)fminf(fmaxf(rintf(v[1] * s4[1] * gq), -128.f), 127.f);
      int q2i = (int)fminf(fmaxf(rintf(v[2] * s4[2] * gq), -128.f), 127.f);
      int q3i = (int)fminf(fmaxf(rintf(v[3] * s4[3] * gq), -128.f), 127.f);
      unsigned p = (unsigned)(q0 & 255) | ((unsigned)(q1i & 255) << 8) |
                   ((unsigned)(q2i & 255) << 16) | ((unsigned)(q3i & 255) << 24);
      *reinterpret_cast<unsigned*>(&q1[token * 848 + (sl + 16 * c) * 4]) = p;
    }
    if (sl < 4) {
      fx4 v = xv[12];
      fx4 s4 = *reinterpret_cast<const fx4*>(sc1 + (sl + 192) * 4);
      int q0 = (int)fminf(fmaxf(rintf(v[0] * s4[0] * gq), -128.f), 127.f);
      int q1i = (int)fminf(fmaxf(rintf(v[1] * s4[1] * gq), -128.f), 127.f);
      int q2i = (int)fminf(fmaxf(rintf(v[2] * s4[2] * gq), -128.f), 127.f);
      int q3i = (int)fminf(fmaxf(rintf(v[3] * s4[3] * gq), -128.f), 127.f);
      unsigned p = (unsigned)(q0 & 255) | ((unsigned)(q1i & 255) << 8) |
                   ((unsigned)(q2i & 255) << 16) | ((unsigned)(q3i & 255) << 24);
      *reinterpret_cast<unsigned*>(&q1[token * 848 + (sl + 192) * 4]) = p;
    }

    // ---- prefetch next tile's x into the now-dead registers ----
    // (skipped entirely on the last iteration; stale regs are never read)
    {
      const int ntile = tile + (int)gridDim.x;
      if (ntile < numTiles) {
        const float* rowp = x + (size_t)(ntile * 16 + token) * 784;
#pragma unroll
        for (int c = 0; c < 12; ++c)
          xv[c] = *reinterpret_cast<const fx4*>(rowp + (sl + 16 * c) * 4);
        if (sl < 4) xv[12] = *reinterpret_cast<const fx4*>(rowp + (sl + 192) * 4);
      }
    }

    sync_lds();  // q1 ready (prefetch loads stay in flight)

    // ---- layer-1 MFMA: M=16, N=128 (wave wv -> cols wv*32..+31), K=832 ----
    ix4 acc0 = {0, 0, 0, 0}, acc1 = {0, 0, 0, 0};
    {
      const int8_t* b0p = t1 + (wv * 32 + sl) * 832;
      const int8_t* b1p = b0p + 16 * 832;
#pragma unroll 4
      for (int kk = 0; kk < 13; ++kk) {
        const int k0 = kk * 64 + g * 16;
        ix4 a  = *reinterpret_cast<const ix4*>(&q1[sl * 848 + k0]);
        ix4 b0 = *reinterpret_cast<const ix4*>(b0p + k0);
        ix4 b1 = *reinterpret_cast<const ix4*>(b1p + k0);
        acc0 = MFMA_I8(a, b0, acc0);
        acc1 = MFMA_I8(a, b1, acc1);
      }
    }
#pragma unroll
    for (int r = 0; r < 4; ++r) {
      const int tr = g * 4 + r;
      const float s = inv1[tr] * m1;
      h1[tr * 132 + wv * 32 + sl]      = fmaxf((float)acc0[r] * s, 0.f);
      h1[tr * 132 + wv * 32 + 16 + sl] = fmaxf((float)acc1[r] * s, 0.f);
    }
    sync_lds();  // h1 ready

    // ---- layer-2 quant: 128 elems/token, 8 per lane ----
    {
      fx4 v0 = *reinterpret_cast<const fx4*>(&h1[token * 132 + sl * 4]);
      fx4 v1 = *reinterpret_cast<const fx4*>(&h1[token * 132 + 64 + sl * 4]);
      fx4 s0 = *reinterpret_cast<const fx4*>(sc2 + sl * 4);
      fx4 s1 = *reinterpret_cast<const fx4*>(sc2 + 64 + sl * 4);
      float ss2 = v0[0]*v0[0] + v0[1]*v0[1] + v0[2]*v0[2] + v0[3]*v0[3]
                + v1[0]*v1[0] + v1[1]*v1[1] + v1[2]*v1[2] + v1[3]*v1[3];
      float am2 = fmaxf(fmaxf(fmaxf(fabsf(v0[0]*s0[0]), fabsf(v0[1]*s0[1])),
                              fmaxf(fabsf(v0[2]*s0[2]), fabsf(v0[3]*s0[3]))),
                        fmaxf(fmaxf(fabsf(v1[0]*s1[0]), fabsf(v1[1]*s1[1])),
                              fmaxf(fabsf(v1[2]*s1[2]), fabsf(v1[3]*s1[3]))));
#pragma unroll
      for (int m = 1; m < 16; m <<= 1) {
        ss2 += __shfl_xor(ss2, m, 64);
        am2 = fmaxf(am2, __shfl_xor(am2, m, 64));
      }
      const float den2 = sqrtf(ss2) * 0.08838834764831845f + 1e-8f; // 1/sqrt(128)
      const float id2  = 1.0f / den2;
      const float cl2  = fmaxf(am2 * id2, 1e-5f);
      const float gq2  = (127.0f / cl2) * id2;
      if (sl == 0) inv2[token] = cl2 * (1.0f / 127.0f);
      int a0 = (int)fminf(fmaxf(rintf(v0[0]*s0[0]*gq2), -128.f), 127.f);
      int a1 = (int)fminf(fmaxf(rintf(v0[1]*s0[1]*gq2), -128.f), 127.f);
      int a2 = (int)fminf(fmaxf(rintf(v0[2]*s0[2]*gq2), -128.f), 127.f);
      int a3 = (int)fminf(fmaxf(rintf(v0[3]*s0[3]*gq2), -128.f), 127.f);
      int b0 = (int)fminf(fmaxf(rintf(v1[0]*s1[0]*gq2), -128.f), 127.f);
      int b1 = (int)fminf(fmaxf(rintf(v1[1]*s1[1]*gq2), -128.f), 127.f);
      int b2 = (int)fminf(fmaxf(rintf(v1[2]*s1[2]*gq2), -128.f), 127.f);
      int b3 = (int)fminf(fmaxf(rintf(v1[3]*s1[3]*gq2), -128.f), 127.f);
      unsigned pa = (unsigned)(a0 & 255) | ((unsigned)(a1 & 255) << 8) |
                    ((unsigned)(a2 & 255) << 16) | ((unsigned)(a3 & 255) << 24);
      unsigned pb = (unsigned)(b0 & 255) | ((unsigned)(b1 & 255) << 8) |
                    ((unsigned)(b2 & 255) << 16) | ((unsigned)(b3 & 255) << 24);
      *reinterpret_cast<unsigned*>(&q2[token * 144 + sl * 4]) = pa;
      *reinterpret_cast<unsigned*>(&q2[token * 144 + 64 + sl * 4]) = pb;
    }
    sync_lds();  // q2 ready

    // ---- layer-2 MFMA: M=16, N=64 (wave wv -> cols wv*16..+15), K=128 ----
    ix4 acc2 = {0, 0, 0, 0};
    {
      const int8_t* bp = t2 + (wv * 16 + sl) * 128;
#pragma unroll
      for (int kk = 0; kk < 2; ++kk) {
        const int k0 = kk * 64 + g * 16;
        ix4 a = *reinterpret_cast<const ix4*>(&q2[sl * 144 + k0]);
        ix4 b = *reinterpret_cast<const ix4*>(bp + k0);
        acc2 = MFMA_I8(a, b, acc2);
      }
    }
#pragma unroll
    for (int r = 0; r < 4; ++r) {
      const int tr = g * 4 + r;
      h2[tr * 68 + wv * 16 + sl] = fmaxf((float)acc2[r] * inv2[tr] * m2, 0.f);
    }
    sync_lds();  // h2 ready

    // ---- layer-3 quant: 64 elems/token, 4 per lane ----
    {
      fx4 v = *reinterpret_cast<const fx4*>(&h2[token * 68 + sl * 4]);
      fx4 s = *reinterpret_cast<const fx4*>(sc3 + sl * 4);
      float ss3 = v[0]*v[0] + v[1]*v[1] + v[2]*v[2] + v[3]*v[3];
      float am3 = fmaxf(fmaxf(fabsf(v[0]*s[0]), fabsf(v[1]*s[1])),
                        fmaxf(fabsf(v[2]*s[2]), fabsf(v[3]*s[3])));
#pragma unroll
      for (int m = 1; m < 16; m <<= 1) {
        ss3 += __shfl_xor(ss3, m, 64);
        am3 = fmaxf(am3, __shfl_xor(am3, m, 64));
      }
      const float den3 = sqrtf(ss3) * 0.125f + 1e-8f;  // 1/sqrt(64)
      const float id3  = 1.0f / den3;
      const float cl3  = fmaxf(am3 * id3, 1e-5f);
      const float gq3  = (127.0f / cl3) * id3;
      if (sl == 0) inv3[token] = cl3 * (1.0f / 127.0f);
      int c0 = (int)fminf(fmaxf(rintf(v[0]*s[0]*gq3), -128.f), 127.f);
      int c1 = (int)fminf(fmaxf(rintf(v[1]*s[1]*gq3), -128.f), 127.f);
      int c2 = (int)fminf(fmaxf(rintf(v[2]*s[2]*gq3), -128.f), 127.f);
      int c3 = (int)fminf(fmaxf(rintf(v[3]*s[3]*gq3), -128.f), 127.f);
      unsigned p = (unsigned)(c0 & 255) | ((unsigned)(c1 & 255) << 8) |
                   ((unsigned)(c2 & 255) << 16) | ((unsigned)(c3 & 255) << 24);
      *reinterpret_cast<unsigned*>(&q3[token * 80 + sl * 4]) = p;
    }
    sync_lds();  // q3 ready

    // ---- layer-3 MFMA: M=16, N=16(10), K=64 — wave 0 only ----
    if (wv == 0) {
      ix4 acc3 = {0, 0, 0, 0};
      ix4 a = *reinterpret_cast<const ix4*>(&q3[sl * 80 + g * 16]);
      ix4 b = *reinterpret_cast<const ix4*>(t3 + sl * 64 + g * 16);
      acc3 = MFMA_I8(a, b, acc3);
      if (sl < 10) {
        const long tok0 = (long)tile * 16;
#pragma unroll
        for (int r = 0; r < 4; ++r) {
          const int tr = g * 4 + r;
          out[(tok0 + tr) * 10 + sl] = (float)acc3[r] * inv3[tr] * m3;
        }
      }
    }
    sync_lds();  // everyone done with q3/h-buffers before next iter's writes
  }
}

// ---------------------------------------------------------------- launch
extern "C" void kernel_launch(void* const* d_in, const int* in_sizes, int n_in,
                              void* d_out, int out_size, void* d_ws, size_t ws_size,
                              hipStream_t stream) {
  const float* x  = (const float*)d_in[0];
  const float* w1 = (const float*)d_in[1];
  const float* s1 = (const float*)d_in[2];
  const float* w2 = (const float*)d_in[3];
  const float* s2 = (const float*)d_in[4];
  const float* w3 = (const float*)d_in[5];
  const float* s3 = (const float*)d_in[6];
  float* out = (float*)d_out;

  char* ws = (char*)d_ws;
  double* sums = (double*)ws;
  int8_t* t1 = (int8_t*)(ws + 256);
  int8_t* t2 = (int8_t*)(ws + 106752);
  int8_t* t3 = (int8_t*)(ws + 114944);

  const int B = in_sizes[0] / 784;
  const int numTiles = B / 16;

  hipMemsetAsync(sums, 0, 3 * sizeof(double), stream);
  prep_mean<<<249, 256, 0, stream>>>(w1, w2, w3, sums);
  const int total_q = 128 * 832 + 64 * 128 + 16 * 64;  // 115712
  prep_quant<<<(total_q + 255) / 256, 256, 0, stream>>>(w1, w2, w3, sums, t1, t2, t3);
  const int grid = numTiles < 1024 ? numTiles : 1024;
  ffn_main<<<grid, 256, 0, stream>>>(x, s1, s2, s3, t1, t2, t3, sums, out, numTiles);
}

// Round 4
// 319.497 us; speedup vs baseline: 1.2585x; 1.0009x over previous
//
#include <hip/hip_runtime.h>
#include <stdint.h>

// BitNet-style fused 3-layer MLP for MI355X (gfx950) — round 4.
//
// Round-3 post-mortem: ffn ~110 us, still ~3x over the 33 us x-read BW
// floor; latency-bound on the 6-barrier serial chain per 16-token tile
// (layers 2+3 are ~0.2 us of math but add 4 barriers + 4 LDS round trips).
// Round-4: split at the L1/L2 boundary.
//   kernel 1 (persistent): x -> stats -> quant -> MFMA1 -> relu -> L2-quant
//     -> write int8 q2 + scales to ws. 2 barriers/tile, LDS 22 KB.
//   kernel 2 (barrier-free): per-wave 16 tokens, A-frags straight from
//     global q2 (row-major == A-layout), MFMA2, in-wave quant3, 1 KB
//     wave-private LDS transpose (lgkmcnt only), MFMA3 vs k-permuted t3p.
//
// ws layout (offsets mult of 256):
//   0        double sums[3]
//   1024     t1:  128 x 832 int8 ternary w1 (K 784->832 zero-pad)   106496 B
//   107520   t2:  64 x 128 int8 ternary w2                            8192 B
//   115712   t3p: 16 x 64  int8 ternary w3, k-permuted, rows 10..15=0 1024 B
//   116736   inv2: float[B]  per-token L2 dequant scale             262144 B
//   378880   q2:  int8[B*128] quantized L2 activations             8388608 B

typedef int   ix4 __attribute__((ext_vector_type(4)));
typedef float fx4 __attribute__((ext_vector_type(4)));

#define MFMA_I8(a, b, c) __builtin_amdgcn_mfma_i32_16x16x64_i8((a), (b), (c), 0, 0, 0)

// Barrier that waits LDS ops only; global loads (prefetch) stay in flight.
__device__ __forceinline__ void sync_lds() {
  asm volatile("s_waitcnt lgkmcnt(0)" ::: "memory");
  __builtin_amdgcn_s_barrier();
}
__device__ __forceinline__ void wave_lds_fence() {
  asm volatile("s_waitcnt lgkmcnt(0)" ::: "memory");
}

// ---------------------------------------------------------------- prep 1
__global__ __launch_bounds__(256) void prep_mean(
    const float* __restrict__ w1, const float* __restrict__ w2,
    const float* __restrict__ w3, double* __restrict__ sums) {
  __shared__ double red[256];
  const int b = blockIdx.x;
  const float* w; int n, nb, bb, which;
  if (b < 240)      { w = w1; n = 128 * 784; nb = 240; bb = b;       which = 0; }
  else if (b < 248) { w = w2; n = 64 * 128;  nb = 8;   bb = b - 240; which = 1; }
  else              { w = w3; n = 10 * 64;   nb = 1;   bb = 0;       which = 2; }
  double s = 0.0;
  for (int i = bb * 256 + (int)threadIdx.x; i < n; i += nb * 256)
    s += (double)fabsf(w[i]);
  red[threadIdx.x] = s;
  __syncthreads();
  for (int off = 128; off > 0; off >>= 1) {
    if ((int)threadIdx.x < off) red[threadIdx.x] += red[threadIdx.x + off];
    __syncthreads();
  }
  if (threadIdx.x == 0) atomicAdd(&sums[which], red[0]);
}

// ---------------------------------------------------------------- prep 2
__global__ __launch_bounds__(256) void prep_quant(
    const float* __restrict__ w1, const float* __restrict__ w2,
    const float* __restrict__ w3, const double* __restrict__ sums,
    int8_t* __restrict__ t1, int8_t* __restrict__ t2,
    int8_t* __restrict__ t3p) {
  const int idx = blockIdx.x * 256 + (int)threadIdx.x;
  const float s1 = 1.0f / fmaxf((float)(sums[0] * (1.0 / (128.0 * 784.0))), 1e-5f);
  const float s2 = 1.0f / fmaxf((float)(sums[1] * (1.0 / (64.0 * 128.0))), 1e-5f);
  const float s3 = 1.0f / fmaxf((float)(sums[2] * (1.0 / (10.0 * 64.0))), 1e-5f);
  if (idx < 128 * 832) {
    const int n = idx / 832, k = idx - n * 832;
    float v = 0.f;
    if (k < 784) v = fminf(fmaxf(rintf(w1[n * 784 + k] * s1), -1.f), 1.f);
    t1[idx] = (int8_t)(int)v;
  } else if (idx < 128 * 832 + 64 * 128) {
    const int i = idx - 128 * 832;
    t2[i] = (int8_t)(int)fminf(fmaxf(rintf(w2[i] * s2), -1.f), 1.f);
  } else if (idx < 128 * 832 + 64 * 128 + 16 * 64) {
    const int i = idx - (128 * 832 + 64 * 128);
    const int n = i >> 6, p = i & 63;
    // k-permutation: A-side packs channel ch = (p>>2) + 16*(p&3) at pos p;
    // permuting B identically leaves the dot product unchanged.
    const int ch = (p >> 2) + 16 * (p & 3);
    float v = 0.f;
    if (n < 10) v = fminf(fmaxf(rintf(w3[n * 64 + ch] * s3), -1.f), 1.f);
    t3p[i] = (int8_t)(int)v;
  }
}

// ---------------------------------------------------------------- kernel 1
// Persistent; 16 tokens/tile; lane roles: wv=wave, g=l>>4, sl=l&15;
// quant token = wv*4+g. i8 MFMA A: A[m=sl][k=64kk+16g+j]; D[4g+r][sl].
__global__ __launch_bounds__(256)
__attribute__((amdgpu_waves_per_eu(2, 4)))
void ffn_l1(
    const float* __restrict__ x,
    const float* __restrict__ sc1, const float* __restrict__ sc2,
    const int8_t* __restrict__ t1, const double* __restrict__ sums,
    int8_t* __restrict__ q2g, float* __restrict__ inv2g, int numTiles) {
  __shared__ int8_t q1[16 * 848];   // 13.6 KB
  __shared__ float  h1[16 * 132];   // 8.4 KB
  __shared__ float  inv1[16];

  const int tid = threadIdx.x;
  const int l   = tid & 63;
  const int wv  = tid >> 6;
  const int g   = l >> 4;
  const int sl  = l & 15;
  const int token = wv * 4 + g;

  const float m1 = fmaxf((float)(sums[0] * (1.0 / (128.0 * 784.0))), 1e-5f);

  // zero q1's K-pad [784,832) once
  if (tid < 192) {
    const int t = tid / 12, c = tid - (tid / 12) * 12;
    *reinterpret_cast<unsigned*>(&q1[t * 848 + 784 + c * 4]) = 0u;
  }

  fx4 xv[13];
  int tile = blockIdx.x;
  if (tile < numTiles) {
    const float* rowp = x + (size_t)(tile * 16 + token) * 784;
#pragma unroll
    for (int c = 0; c < 12; ++c)
      xv[c] = *reinterpret_cast<const fx4*>(rowp + (sl + 16 * c) * 4);
    if (sl < 4) xv[12] = *reinterpret_cast<const fx4*>(rowp + (sl + 192) * 4);
  }

  for (; tile < numTiles; tile += (int)gridDim.x) {
    // ---- stats: sumsq(x) + max|sc1*x| ----
    float ss = 0.f, am = 0.f;
#pragma unroll
    for (int c = 0; c < 12; ++c) {
      fx4 v = xv[c];
      fx4 s4 = *reinterpret_cast<const fx4*>(sc1 + (sl + 16 * c) * 4);
      ss += v[0] * v[0] + v[1] * v[1] + v[2] * v[2] + v[3] * v[3];
      am = fmaxf(am, fmaxf(fmaxf(fabsf(v[0] * s4[0]), fabsf(v[1] * s4[1])),
                           fmaxf(fabsf(v[2] * s4[2]), fabsf(v[3] * s4[3]))));
    }
    if (sl < 4) {
      fx4 v = xv[12];
      fx4 s4 = *reinterpret_cast<const fx4*>(sc1 + (sl + 192) * 4);
      ss += v[0] * v[0] + v[1] * v[1] + v[2] * v[2] + v[3] * v[3];
      am = fmaxf(am, fmaxf(fmaxf(fabsf(v[0] * s4[0]), fabsf(v[1] * s4[1])),
                           fmaxf(fabsf(v[2] * s4[2]), fabsf(v[3] * s4[3]))));
    }
#pragma unroll
    for (int m = 1; m < 16; m <<= 1) {
      ss += __shfl_xor(ss, m, 64);
      am = fmaxf(am, __shfl_xor(am, m, 64));
    }
    const float denom = sqrtf(ss) * (1.0f / 28.0f) + 1e-8f;
    const float invd  = 1.0f / denom;
    const float cl    = fmaxf(am * invd, 1e-5f);
    const float gq    = (127.0f / cl) * invd;
    if (sl == 0) inv1[token] = cl * (1.0f / 127.0f);

    // ---- quantize from regs into LDS (packed int8) ----
#pragma unroll
    for (int c = 0; c < 12; ++c) {
      fx4 v = xv[c];
      fx4 s4 = *reinterpret_cast<const fx4*>(sc1 + (sl + 16 * c) * 4);
      int q0 = (int)fminf(fmaxf(rintf(v[0] * s4[0] * gq), -128.f), 127.f);
      int q1i = (int)fminf(fmaxf(rintf(v[1] * s4[1] * gq), -128.f), 127.f);
      int q2i = (int)fminf(fmaxf(rintf(v[2] * s4[2] * gq), -128.f), 127.f);
      int q3i = (int)fminf(fmaxf(rintf(v[3] * s4[3] * gq), -128.f), 127.f);
      unsigned p = (unsigned)(q0 & 255) | ((unsigned)(q1i & 255) << 8) |
                   ((unsigned)(q2i & 255) << 16) | ((unsigned)(q3i & 255) << 24);
      *reinterpret_cast<unsigned*>(&q1[token * 848 + (sl + 16 * c) * 4]) = p;
    }
    if (sl < 4) {
      fx4 v = xv[12];
      fx4 s4 = *reinterpret_cast<const fx4*>(sc1 + (sl + 192) * 4);
      int q0 = (int)fminf(fmaxf(rintf(v[0] * s4[0] * gq), -128.f), 127.f);
      int q1i = (int)fminf(fmaxf(rintf(v[1] * s4[1] * gq), -128.f), 127.f);
      int q2i = (int)fminf(fmaxf(rintf(v[2] * s4[2] * gq), -128.f), 127.f);
      int q3i = (int)fminf(fmaxf(rintf(v[3] * s4[3] * gq), -128.f), 127.f);
      unsigned p = (unsigned)(q0 & 255) | ((unsigned)(q1i & 255) << 8) |
                   ((unsigned)(q2i & 255) << 16) | ((unsigned)(q3i & 255) << 24);
      *reinterpret_cast<unsigned*>(&q1[token * 848 + (sl + 192) * 4]) = p;
    }

    // ---- prefetch next tile's x into the now-dead registers ----
    {
      const int ntile = tile + (int)gridDim.x;
      if (ntile < numTiles) {
        const float* rowp = x + (size_t)(ntile * 16 + token) * 784;
#pragma unroll
        for (int c = 0; c < 12; ++c)
          xv[c] = *reinterpret_cast<const fx4*>(rowp + (sl + 16 * c) * 4);
        if (sl < 4) xv[12] = *reinterpret_cast<const fx4*>(rowp + (sl + 192) * 4);
      }
    }

    sync_lds();  // BAR1: q1 ready (prefetch stays in flight)

    // ---- MFMA1: M=16, N=128 (wave wv -> cols wv*32..+31), K=832 ----
    ix4 acc0 = {0, 0, 0, 0}, acc1 = {0, 0, 0, 0};
    {
      const int8_t* b0p = t1 + (wv * 32 + sl) * 832;
      const int8_t* b1p = b0p + 16 * 832;
#pragma unroll 4
      for (int kk = 0; kk < 13; ++kk) {
        const int k0 = kk * 64 + g * 16;
        ix4 a  = *reinterpret_cast<const ix4*>(&q1[sl * 848 + k0]);
        ix4 b0 = *reinterpret_cast<const ix4*>(b0p + k0);
        ix4 b1 = *reinterpret_cast<const ix4*>(b1p + k0);
        acc0 = MFMA_I8(a, b0, acc0);
        acc1 = MFMA_I8(a, b1, acc1);
      }
    }
#pragma unroll
    for (int r = 0; r < 4; ++r) {
      const int tr = g * 4 + r;
      const float s = inv1[tr] * m1;
      h1[tr * 132 + wv * 32 + sl]      = fmaxf((float)acc0[r] * s, 0.f);
      h1[tr * 132 + wv * 32 + 16 + sl] = fmaxf((float)acc1[r] * s, 0.f);
    }
    sync_lds();  // BAR2: h1 ready

    // ---- layer-2 quant: per token, 8 elems/lane; q2 -> GLOBAL ----
    {
      fx4 v0 = *reinterpret_cast<const fx4*>(&h1[token * 132 + sl * 4]);
      fx4 v1 = *reinterpret_cast<const fx4*>(&h1[token * 132 + 64 + sl * 4]);
      fx4 s0 = *reinterpret_cast<const fx4*>(sc2 + sl * 4);
      fx4 s1 = *reinterpret_cast<const fx4*>(sc2 + 64 + sl * 4);
      float ss2 = v0[0]*v0[0] + v0[1]*v0[1] + v0[2]*v0[2] + v0[3]*v0[3]
                + v1[0]*v1[0] + v1[1]*v1[1] + v1[2]*v1[2] + v1[3]*v1[3];
      float am2 = fmaxf(fmaxf(fmaxf(fabsf(v0[0]*s0[0]), fabsf(v0[1]*s0[1])),
                              fmaxf(fabsf(v0[2]*s0[2]), fabsf(v0[3]*s0[3]))),
                        fmaxf(fmaxf(fabsf(v1[0]*s1[0]), fabsf(v1[1]*s1[1])),
                              fmaxf(fabsf(v1[2]*s1[2]), fabsf(v1[3]*s1[3]))));
#pragma unroll
      for (int m = 1; m < 16; m <<= 1) {
        ss2 += __shfl_xor(ss2, m, 64);
        am2 = fmaxf(am2, __shfl_xor(am2, m, 64));
      }
      const float den2 = sqrtf(ss2) * 0.08838834764831845f + 1e-8f; // 1/sqrt(128)
      const float id2  = 1.0f / den2;
      const float cl2  = fmaxf(am2 * id2, 1e-5f);
      const float gq2  = (127.0f / cl2) * id2;
      const size_t tok = (size_t)tile * 16 + token;
      if (sl == 0) inv2g[tok] = cl2 * (1.0f / 127.0f);
      int a0 = (int)fminf(fmaxf(rintf(v0[0]*s0[0]*gq2), -128.f), 127.f);
      int a1 = (int)fminf(fmaxf(rintf(v0[1]*s0[1]*gq2), -128.f), 127.f);
      int a2 = (int)fminf(fmaxf(rintf(v0[2]*s0[2]*gq2), -128.f), 127.f);
      int a3 = (int)fminf(fmaxf(rintf(v0[3]*s0[3]*gq2), -128.f), 127.f);
      int b0 = (int)fminf(fmaxf(rintf(v1[0]*s1[0]*gq2), -128.f), 127.f);
      int b1 = (int)fminf(fmaxf(rintf(v1[1]*s1[1]*gq2), -128.f), 127.f);
      int b2 = (int)fminf(fmaxf(rintf(v1[2]*s1[2]*gq2), -128.f), 127.f);
      int b3 = (int)fminf(fmaxf(rintf(v1[3]*s1[3]*gq2), -128.f), 127.f);
      unsigned pa = (unsigned)(a0 & 255) | ((unsigned)(a1 & 255) << 8) |
                    ((unsigned)(a2 & 255) << 16) | ((unsigned)(a3 & 255) << 24);
      unsigned pb = (unsigned)(b0 & 255) | ((unsigned)(b1 & 255) << 8) |
                    ((unsigned)(b2 & 255) << 16) | ((unsigned)(b3 & 255) << 24);
      *reinterpret_cast<unsigned*>(q2g + tok * 128 + sl * 4)      = pa;
      *reinterpret_cast<unsigned*>(q2g + tok * 128 + 64 + sl * 4) = pb;
    }
    // next iteration's q1 writes are safe: all waves passed BAR2 (q1 reads
    // done); h1 overwrite happens only after next BAR1 (quant2 reads done).
  }
}

// ---------------------------------------------------------------- kernel 2
// Layers 2+3, barrier-free: each wave owns 16 tokens end-to-end.
__global__ __launch_bounds__(256) void ffn_l23(
    const int8_t* __restrict__ q2g, const float* __restrict__ inv2g,
    const float* __restrict__ sc3,
    const int8_t* __restrict__ t2, const int8_t* __restrict__ t3p,
    const double* __restrict__ sums, float* __restrict__ out) {
  __shared__ int8_t wbuf[4][16 * 64];  // wave-private transpose buffers

  const int tid = threadIdx.x;
  const int l   = tid & 63;
  const int wv  = tid >> 6;
  const int g   = l >> 4;
  const int sl  = l & 15;
  const int wtok0 = (blockIdx.x * 4 + wv) * 16;

  const float m2 = fmaxf((float)(sums[1] * (1.0 / (64.0 * 128.0))), 1e-5f);
  const float m3 = fmaxf((float)(sums[2] * (1.0 / (10.0 * 64.0))), 1e-5f);

  // A-fragments straight from global q2 (row-major == A-layout)
  ix4 a0 = *reinterpret_cast<const ix4*>(q2g + (size_t)(wtok0 + sl) * 128 + g * 16);
  ix4 a1 = *reinterpret_cast<const ix4*>(q2g + (size_t)(wtok0 + sl) * 128 + 64 + g * 16);
  fx4 i2 = *reinterpret_cast<const fx4*>(inv2g + wtok0 + 4 * g);  // tokens 4g..4g+3

  // MFMA2: M=16 (tokens), N=64 -> 4 n-tiles, K=128 -> 2 k-steps
  ix4 acc[4];
#pragma unroll
  for (int nt = 0; nt < 4; ++nt) {
    ix4 c = {0, 0, 0, 0};
    const int8_t* bp = t2 + (nt * 16 + sl) * 128;
    c = MFMA_I8(a0, *reinterpret_cast<const ix4*>(bp + g * 16), c);
    c = MFMA_I8(a1, *reinterpret_cast<const ix4*>(bp + 64 + g * 16), c);
    acc[nt] = c;
  }

  // lane (g,sl) holds h2 for tokens 4g+r (r=0..3), channels nt*16+sl
  float sc3v[4];
#pragma unroll
  for (int nt = 0; nt < 4; ++nt) sc3v[nt] = sc3[nt * 16 + sl];

  float h2v[4][4];  // [nt][r]
  float ss3[4] = {0.f, 0.f, 0.f, 0.f}, am3[4] = {0.f, 0.f, 0.f, 0.f};
#pragma unroll
  for (int nt = 0; nt < 4; ++nt)
#pragma unroll
    for (int r = 0; r < 4; ++r) {
      float h = fmaxf((float)acc[nt][r] * i2[r] * m2, 0.f);
      h2v[nt][r] = h;
      ss3[r] += h * h;
      am3[r] = fmaxf(am3[r], fabsf(h * sc3v[nt]));
    }
#pragma unroll
  for (int m = 1; m < 16; m <<= 1) {
#pragma unroll
    for (int r = 0; r < 4; ++r) {
      ss3[r] += __shfl_xor(ss3[r], m, 64);
      am3[r] = fmaxf(am3[r], __shfl_xor(am3[r], m, 64));
    }
  }
  float gq3[4], i3[4];
#pragma unroll
  for (int r = 0; r < 4; ++r) {
    const float den3 = sqrtf(ss3[r]) * 0.125f + 1e-8f;  // 1/sqrt(64)
    const float id3  = 1.0f / den3;
    const float cl3  = fmaxf(am3[r] * id3, 1e-5f);
    gq3[r] = (127.0f / cl3) * id3;
    i3[r]  = cl3 * (1.0f / 127.0f) * m3;
  }

  // quant3 + transpose through wave-private LDS (k-permuted order: pos
  // p = sl*4+nt holds channel nt*16+sl, matching t3p's permutation)
#pragma unroll
  for (int r = 0; r < 4; ++r) {
    int c0 = (int)fminf(fmaxf(rintf(h2v[0][r] * sc3v[0] * gq3[r]), -128.f), 127.f);
    int c1 = (int)fminf(fmaxf(rintf(h2v[1][r] * sc3v[1] * gq3[r]), -128.f), 127.f);
    int c2 = (int)fminf(fmaxf(rintf(h2v[2][r] * sc3v[2] * gq3[r]), -128.f), 127.f);
    int c3 = (int)fminf(fmaxf(rintf(h2v[3][r] * sc3v[3] * gq3[r]), -128.f), 127.f);
    unsigned p = (unsigned)(c0 & 255) | ((unsigned)(c1 & 255) << 8) |
                 ((unsigned)(c2 & 255) << 16) | ((unsigned)(c3 & 255) << 24);
    *reinterpret_cast<unsigned*>(&wbuf[wv][(4 * g + r) * 64 + sl * 4]) = p;
  }
  wave_lds_fence();  // same-wave write->read, no barrier needed

  // MFMA3: M=16 tokens, N=16 (10 used), K=64 (permuted)
  ix4 a3 = *reinterpret_cast<const ix4*>(&wbuf[wv][sl * 64 + g * 16]);
  ix4 b3 = *reinterpret_cast<const ix4*>(t3p + sl * 64 + g * 16);
  ix4 acc3 = {0, 0, 0, 0};
  acc3 = MFMA_I8(a3, b3, acc3);

  if (sl < 10) {
#pragma unroll
    for (int r = 0; r < 4; ++r)
      out[(size_t)(wtok0 + 4 * g + r) * 10 + sl] = (float)acc3[r] * i3[r];
  }
}

// ---------------------------------------------------------------- launch
extern "C" void kernel_launch(void* const* d_in, const int* in_sizes, int n_in,
                              void* d_out, int out_size, void* d_ws, size_t ws_size,
                              hipStream_t stream) {
  const float* x  = (const float*)d_in[0];
  const float* w1 = (const float*)d_in[1];
  const float* s1 = (const float*)d_in[2];
  const float* w2 = (const float*)d_in[3];
  const float* s2 = (const float*)d_in[4];
  const float* w3 = (const float*)d_in[5];
  const float* s3 = (const float*)d_in[6];
  float* out = (float*)d_out;

  char* ws = (char*)d_ws;
  double* sums = (double*)ws;
  int8_t* t1   = (int8_t*)(ws + 1024);
  int8_t* t2   = (int8_t*)(ws + 107520);
  int8_t* t3p  = (int8_t*)(ws + 115712);
  float*  inv2 = (float*)(ws + 116736);
  int8_t* q2   = (int8_t*)(ws + 378880);

  const int B = in_sizes[0] / 784;
  const int numTiles = B / 16;

  hipMemsetAsync(sums, 0, 3 * sizeof(double), stream);
  prep_mean<<<249, 256, 0, stream>>>(w1, w2, w3, sums);
  const int total_q = 128 * 832 + 64 * 128 + 16 * 64;  // 115712
  prep_quant<<<(total_q + 255) / 256, 256, 0, stream>>>(w1, w2, w3, sums, t1, t2, t3p);
  const int grid1 = numTiles < 1024 ? numTiles : 1024;
  ffn_l1<<<grid1, 256, 0, stream>>>(x, s1, s2, t1, sums, q2, inv2, numTiles);
  ffn_l23<<<B / 64, 256, 0, stream>>>(q2, inv2, s3, t2, t3p, sums, out);
}